// Round 14
// baseline (57.566 us; speedup 1.0000x reference)
//
#include <hip/hip_runtime.h>
#include <math.h>

// x: [128,128,128,16] f32 ; MaxPool3d win 4 stride 2 -> pooled [63,63,63,16]
// patches: 30^3 cubes of 4^3 at stride 2 -> out (27000, 64, 16) f32
// Identity: pooled[dp] = max(pair[dp], pair[dp+1]), pair[t] = max(d-rows 2t,2t+1).
// Phase 1: streaming hw-pool + d-PAIR fold -> hwp2[t=63][hp=63][wp=63][c=16] (16 MB)
//          x loads NONTEMPORAL (read-once) so hwp2 stays L2-resident for phase 2.
// Phase 2: per-patch-run slab gather: LDS slab [5][4][14], 2-way d-fold, NT emit.
#define D0 128
#define NC 16
#define DPE 63
#define NP 30
#define NBLK1 (DPE*4)      // 252
#define NBLK2 (NP*NP*5)    // 4500

typedef float f32x4 __attribute__((ext_vector_type(4)));

__device__ __forceinline__ float4 f4max(float4 a, float4 b) {
    return make_float4(fmaxf(a.x, b.x), fmaxf(a.y, b.y), fmaxf(a.z, b.z), fmaxf(a.w, b.w));
}
__device__ __forceinline__ float4 shfl_down4(float4 v, int d) {
    return make_float4(__shfl_down(v.x, d, 64), __shfl_down(v.y, d, 64),
                       __shfl_down(v.z, d, 64), __shfl_down(v.w, d, 64));
}
__device__ __forceinline__ int xcd_swz(int bid, int nwg) {
    const int q = nwg >> 3, r = nwg & 7;
    const int xcd = bid & 7, idx = bid >> 3;
    return (xcd < r ? xcd * (q + 1) : r * (q + 1) + (xcd - r) * q) + idx;
}

// ---------------- Phase 1: dense-streaming hw-pool + d-pair fold ----------------
// jobs (t, hq), XCD-chunked so each XCD owns a contiguous t-range (aligns with
// phase 2's i-chunking for hwp2 L2 locality). 576 threads = 9 waves; wave s owns
// w=14s..14s+15 (intra-block w-overlap is L1-absorbed).
__global__ __launch_bounds__(576) void hw_pool_pair(const float* __restrict__ x,
                                                    float* __restrict__ hwp2) {
    const int job = xcd_swz(blockIdx.x, NBLK1);
    const int t = job >> 2;              // d-pair index 0..62
    const int hq = job & 3;              // h-quarter
    const int s = threadIdx.x >> 6;      // wave 0..8
    const int lane = threadIdx.x & 63;
    const int wl = lane >> 2;            // 0..15
    const int c4 = lane & 3;
    const int w = 14 * s + wl;           // 0..127

    const int tt0 = 16 * hq;                       // h-pair range [tt0, tt1]
    const int tt1 = min(16 * hq + 16, DPE);        // emit hp = tt-1

    const size_t rowstep = (size_t)D0 * NC;        // 2048 floats per h row
    const float* base0 = x + ((size_t)(2 * t) * D0 * D0 + w) * NC + c4 * 4;
    const float* base1 = base0 + (size_t)D0 * D0 * NC;

    const bool emit = ((wl & 1) == 0) && (wl <= 12);
    const int wp = 7 * s + (wl >> 1);              // 0..62, each exactly once
    float* outb = hwp2 + ((size_t)t * DPE * DPE + wp) * NC + c4 * 4;

    // nontemporal read-once stream; clamp to range end (no over-prefetch waste)
#define LDR(B, h) ({ const int hh_ = min(h, 2 * tt1 + 1); \
        const f32x4 t_ = __builtin_nontemporal_load( \
            reinterpret_cast<const f32x4*>((B) + (size_t)hh_ * rowstep)); \
        make_float4(t_.x, t_.y, t_.z, t_.w); })

    float4 c0 = LDR(base0, 2 * tt0),     c1 = LDR(base0, 2 * tt0 + 1);
    float4 c2 = LDR(base1, 2 * tt0),     c3 = LDR(base1, 2 * tt0 + 1);
    float4 n0 = LDR(base0, 2 * tt0 + 2), n1 = LDR(base0, 2 * tt0 + 3);
    float4 n2 = LDR(base1, 2 * tt0 + 2), n3 = LDR(base1, 2 * tt0 + 3);
    float4 prev = make_float4(-INFINITY, -INFINITY, -INFINITY, -INFINITY);

    for (int tt = tt0; tt <= tt1; ++tt) {
        float4 m0 = LDR(base0, 2 * tt + 4), m1 = LDR(base0, 2 * tt + 5);
        float4 m2 = LDR(base1, 2 * tt + 4), m3 = LDR(base1, 2 * tt + 5);
        const float4 pair = f4max(f4max(c0, c1), f4max(c2, c3));  // d+h pair fold
        if (tt > tt0) {
            const float4 win = f4max(prev, pair);              // h rows 2(tt-1)..2tt+1
            const float4 s1 = f4max(win, shfl_down4(win, 4));  // + w+1
            const float4 s2 = f4max(s1, shfl_down4(s1, 8));    // + w+2, w+3
            if (emit)
                *reinterpret_cast<float4*>(outb + (size_t)(tt - 1) * (DPE * NC)) = s2;
        }
        prev = pair;
        c0 = n0; c1 = n1; c2 = n2; c3 = n3;
        n0 = m0; n1 = m1; n2 = m2; n3 = m3;
    }
#undef LDR
}

// ---------------- Phase 2: slab gather with 2-way d-fold ----------------
// block = (i, j, ks): slab = hwp2[2i..2i+4][2j..2j+3][12ks..12ks+13][:] -> LDS
// (wp padded 14->15), pooled[2i+a] = max(slab[a], slab[a+1]); 6 patches NT-emitted.
__global__ __launch_bounds__(256) void slab_gather2(const float* __restrict__ hwp2,
                                                    float* __restrict__ out) {
    const int b = xcd_swz(blockIdx.x, NBLK2);
    const int i = b / 150;
    const int rem = b % 150;
    const int j = rem / 5;
    const int ks = rem % 5;
    const int tid = threadIdx.x;

    __shared__ float4 slab[5 * 4 * 15 * 4];   // [t_l][hp_l][wp_l pad15][c4] = 19200 B

    for (int it = 0; it < 5; ++it) {
        const int f = tid + 256 * it;
        if (f < 1120) {
            const int t_l = f / 224;           // [5]
            const int r224 = f - t_l * 224;
            const int hp_l = r224 / 56;        // [4]
            const int r56 = r224 - hp_l * 56;
            const int wp_l = r56 >> 2;         // [14]
            const int c4 = f & 3;
            const size_t g = ((size_t)(2 * i + t_l) * DPE + (2 * j + hp_l)) * DPE
                           + (12 * ks + wp_l);
            slab[((t_l * 4 + hp_l) * 15 + wp_l) * 4 + c4] =
                *reinterpret_cast<const float4*>(&hwp2[g * NC + c4 * 4]);
        }
    }
    __syncthreads();

    const int a  = (tid >> 6) & 3;
    const int bb = (tid >> 4) & 3;
    const int cc = (tid >> 2) & 3;
    const int c4 = tid & 3;
    const size_t obase = ((size_t)(i * NP + j) * NP + 6 * ks) * 256;  // float4 units
#pragma unroll
    for (int kl = 0; kl < 6; ++kl) {
        const int wp_l = 2 * kl + cc;
        const int base16 = ((a * 4 + bb) * 15 + wp_l) * 4 + c4;
        const float4 m = f4max(slab[base16], slab[base16 + 240]);  // 240 = 4*15*4
        const f32x4 v = {m.x, m.y, m.z, m.w};
        __builtin_nontemporal_store(v, reinterpret_cast<f32x4*>(&out[(obase + kl * 256 + tid) * 4]));
    }
}

// ---------------- Fallback: verified round-11 fused kernel (no workspace) ----------------
__global__ __launch_bounds__(256) void fused_pool_patch(const float* __restrict__ x,
                                                        float* __restrict__ out) {
    const int b = xcd_swz(blockIdx.x, NBLK2);
    const int i  = b / 150;
    const int rem = b % 150;
    const int j  = rem / 5;
    const int ks = rem % 5;
    const int wave = threadIdx.x >> 6;
    const int lane = threadIdx.x & 63;
    const int dg = wave & 1;
    const int wh = wave >> 1;
    const int c4 = lane & 3;
    const int wl = lane >> 2;
    const int w = 24 * ks + 14 * wh + wl;
    const int dbase = 4 * i + 4 * dg;
    const int hbase = 4 * j;
    float4 acc[2][4];
#pragma unroll
    for (int p = 0; p < 2; ++p)
#pragma unroll
        for (int hh = 0; hh < 4; ++hh)
            acc[p][hh] = make_float4(-INFINITY, -INFINITY, -INFINITY, -INFINITY);
#pragma unroll
    for (int dl = 0; dl < 6; ++dl) {
        const size_t rowb = ((size_t)(dbase + dl) * D0 + hbase) * D0 + w;
        float4 rw[10];
#pragma unroll
        for (int hl = 0; hl < 10; ++hl)
            rw[hl] = *reinterpret_cast<const float4*>(&x[(rowb + hl * D0) * NC + c4 * 4]);
#pragma unroll
        for (int hl = 0; hl < 10; ++hl) {
#pragma unroll
            for (int hpl = 0; hpl < 4; ++hpl) {
                if (hl >= 2 * hpl && hl <= 2 * hpl + 3) {
                    if (dl <= 3) acc[0][hpl] = f4max(acc[0][hpl], rw[hl]);
                    if (dl >= 2) acc[1][hpl] = f4max(acc[1][hpl], rw[hl]);
                }
            }
        }
    }
    __shared__ float plds[4 * 4 * 14 * 16];
    const bool emit = ((wl & 1) == 0) && (wl <= 12);
    const int wpl0 = 7 * wh + (wl >> 1);
#pragma unroll
    for (int dpl = 0; dpl < 2; ++dpl) {
#pragma unroll
        for (int hpl = 0; hpl < 4; ++hpl) {
            const float4 v = acc[dpl][hpl];
            const float4 m1 = f4max(v, shfl_down4(v, 4));
            const float4 m2 = f4max(m1, shfl_down4(m1, 8));
            if (emit) {
                const int a = 2 * dg + dpl;
                *reinterpret_cast<float4*>(&plds[(((a * 4 + hpl) * 14 + wpl0) * 4 + c4) * 4]) = m2;
            }
        }
    }
    __syncthreads();
    const size_t obase = ((size_t)(i * 30 + j) * 30 + 6 * ks) * 256;
#pragma unroll
    for (int rr = 0; rr < 6; ++rr) {
        const int f = threadIdx.x + 256 * rr;
        const int rowq = (f >> 2) & 63;
        const int c4e = f & 3;
        const int a  = rowq >> 4;
        const int bbq = (rowq >> 2) & 3;
        const int cc = rowq & 3;
        const int wpl = 2 * (f >> 8) + cc;
        const f32x4 v = *reinterpret_cast<const f32x4*>(
            &plds[(((a * 4 + bbq) * 14 + wpl) * 4 + c4e) * 4]);
        __builtin_nontemporal_store(v, reinterpret_cast<f32x4*>(&out[(obase + f) * 4]));
    }
}

extern "C" void kernel_launch(void* const* d_in, const int* in_sizes, int n_in,
                              void* d_out, int out_size, void* d_ws, size_t ws_size,
                              hipStream_t stream) {
    const float* x = (const float*)d_in[0];
    float* out = (float*)d_out;

    const size_t hwp2_bytes = (size_t)DPE * DPE * DPE * NC * sizeof(float);  // 16 MB
    if (ws_size >= hwp2_bytes) {
        float* hwp2 = (float*)d_ws;
        hw_pool_pair<<<NBLK1, 576, 0, stream>>>(x, hwp2);
        slab_gather2<<<NBLK2, 256, 0, stream>>>(hwp2, out);
    } else {
        fused_pool_patch<<<NBLK2, 256, 0, stream>>>(x, out);
    }
}

// Round 15
// 51.914 us; speedup vs baseline: 1.1089x; 1.1089x over previous
//
#include <hip/hip_runtime.h>
#include <math.h>

// x: [128,128,128,16] f32 ; MaxPool3d win 4 stride 2 -> pooled [63,63,63,16]
// patches: 30^3 cubes of 4^3 at stride 2 -> out (27000, 64, 16) f32
// Identity: pooled[dp] = max(pair[dp], pair[dp+1]), pair[t] = max(d-rows 2t,2t+1).
// Phase 1: streaming hw-pool + d-PAIR fold -> hwp2[t=63][hp=63][wp=63][c=16] (16 MB)
// Phase 2: per-patch-run slab gather: LDS slab [5][4][14], 2-way d-fold, NT emit.
#define D0 128
#define NC 16
#define DPE 63
#define NP 30
#define HSPL 8             // h-range split per d-pair (parallelism)
#define NBLK1 (DPE*HSPL)   // 504
#define NBLK2 (NP*NP*5)    // 4500

typedef float f32x4 __attribute__((ext_vector_type(4)));

__device__ __forceinline__ float4 f4max(float4 a, float4 b) {
    return make_float4(fmaxf(a.x, b.x), fmaxf(a.y, b.y), fmaxf(a.z, b.z), fmaxf(a.w, b.w));
}
__device__ __forceinline__ float4 shfl_down4(float4 v, int d) {
    return make_float4(__shfl_down(v.x, d, 64), __shfl_down(v.y, d, 64),
                       __shfl_down(v.z, d, 64), __shfl_down(v.w, d, 64));
}
__device__ __forceinline__ int xcd_swz(int bid, int nwg) {
    const int q = nwg >> 3, r = nwg & 7;
    const int xcd = bid & 7, idx = bid >> 3;
    return (xcd < r ? xcd * (q + 1) : r * (q + 1) + (xcd - r) * q) + idx;
}

// ---------------- Phase 1: dense-streaming hw-pool + d-pair fold ----------------
// jobs (t, ho): 63*8 = 504 blocks (~18 waves/CU), XCD-chunked so each XCD owns a
// contiguous t-range. 576 threads = 9 waves; wave s owns w=14s..14s+15 (plain
// cached loads: L1/L2 absorb the 1.125x inter-wave w-overlap).
__global__ __launch_bounds__(576) void hw_pool_pair(const float* __restrict__ x,
                                                    float* __restrict__ hwp2) {
    const int job = xcd_swz(blockIdx.x, NBLK1);
    const int t = job >> 3;              // d-pair index 0..62
    const int ho = job & 7;              // h-range eighth
    const int s = threadIdx.x >> 6;      // wave 0..8
    const int lane = threadIdx.x & 63;
    const int wl = lane >> 2;            // 0..15
    const int c4 = lane & 3;
    const int w = 14 * s + wl;           // 0..127

    const int tt0 = 8 * ho;                        // h-pair range [tt0, tt1]
    const int tt1 = min(8 * ho + 8, DPE);          // emit hp = tt-1 in [tt0, tt1-1]

    const size_t rowstep = (size_t)D0 * NC;        // 2048 floats per h row
    const float* base0 = x + ((size_t)(2 * t) * D0 * D0 + w) * NC + c4 * 4;
    const float* base1 = base0 + (size_t)D0 * D0 * NC;

    const bool emit = ((wl & 1) == 0) && (wl <= 12);
    const int wp = 7 * s + (wl >> 1);              // 0..62, each exactly once
    float* outb = hwp2 + ((size_t)t * DPE * DPE + wp) * NC + c4 * 4;

#define LDR(B, h) (*reinterpret_cast<const float4*>((B) + (size_t)min(h, 2 * tt1 + 1) * rowstep))
    // depth-2 pipeline over h-pairs; each h-pair = 4 rows (2 h x 2 d)
    float4 c0 = LDR(base0, 2 * tt0),     c1 = LDR(base0, 2 * tt0 + 1);
    float4 c2 = LDR(base1, 2 * tt0),     c3 = LDR(base1, 2 * tt0 + 1);
    float4 n0 = LDR(base0, 2 * tt0 + 2), n1 = LDR(base0, 2 * tt0 + 3);
    float4 n2 = LDR(base1, 2 * tt0 + 2), n3 = LDR(base1, 2 * tt0 + 3);
    float4 prev = make_float4(-INFINITY, -INFINITY, -INFINITY, -INFINITY);

    for (int tt = tt0; tt <= tt1; ++tt) {
        float4 m0 = LDR(base0, 2 * tt + 4), m1 = LDR(base0, 2 * tt + 5);
        float4 m2 = LDR(base1, 2 * tt + 4), m3 = LDR(base1, 2 * tt + 5);
        const float4 pair = f4max(f4max(c0, c1), f4max(c2, c3));  // d+h pair fold
        if (tt > tt0) {
            const float4 win = f4max(prev, pair);              // h rows 2(tt-1)..2tt+1
            const float4 s1 = f4max(win, shfl_down4(win, 4));  // + w+1
            const float4 s2 = f4max(s1, shfl_down4(s1, 8));    // + w+2, w+3
            if (emit)
                *reinterpret_cast<float4*>(outb + (size_t)(tt - 1) * (DPE * NC)) = s2;
        }
        prev = pair;
        c0 = n0; c1 = n1; c2 = n2; c3 = n3;
        n0 = m0; n1 = m1; n2 = m2; n3 = m3;
    }
#undef LDR
}

// ---------------- Phase 2: slab gather with 2-way d-fold ----------------
// block = (i, j, ks): slab = hwp2[2i..2i+4][2j..2j+3][12ks..12ks+13][:] -> LDS
// (wp padded 14->15), pooled[2i+a] = max(slab[a], slab[a+1]); 6 patches NT-emitted.
__global__ __launch_bounds__(256) void slab_gather2(const float* __restrict__ hwp2,
                                                    float* __restrict__ out) {
    const int b = xcd_swz(blockIdx.x, NBLK2);
    const int i = b / 150;
    const int rem = b % 150;
    const int j = rem / 5;
    const int ks = rem % 5;
    const int tid = threadIdx.x;

    __shared__ float4 slab[5 * 4 * 15 * 4];   // [t_l][hp_l][wp_l pad15][c4] = 19200 B

    for (int it = 0; it < 5; ++it) {
        const int f = tid + 256 * it;
        if (f < 1120) {
            const int t_l = f / 224;           // [5]
            const int r224 = f - t_l * 224;
            const int hp_l = r224 / 56;        // [4]
            const int r56 = r224 - hp_l * 56;
            const int wp_l = r56 >> 2;         // [14]
            const int c4 = f & 3;
            const size_t g = ((size_t)(2 * i + t_l) * DPE + (2 * j + hp_l)) * DPE
                           + (12 * ks + wp_l);
            slab[((t_l * 4 + hp_l) * 15 + wp_l) * 4 + c4] =
                *reinterpret_cast<const float4*>(&hwp2[g * NC + c4 * 4]);
        }
    }
    __syncthreads();

    const int a  = (tid >> 6) & 3;
    const int bb = (tid >> 4) & 3;
    const int cc = (tid >> 2) & 3;
    const int c4 = tid & 3;
    const size_t obase = ((size_t)(i * NP + j) * NP + 6 * ks) * 256;  // float4 units
#pragma unroll
    for (int kl = 0; kl < 6; ++kl) {
        const int wp_l = 2 * kl + cc;
        const int base16 = ((a * 4 + bb) * 15 + wp_l) * 4 + c4;
        const float4 m = f4max(slab[base16], slab[base16 + 240]);  // 240 = 4*15*4
        const f32x4 v = {m.x, m.y, m.z, m.w};
        __builtin_nontemporal_store(v, reinterpret_cast<f32x4*>(&out[(obase + kl * 256 + tid) * 4]));
    }
}

// ---------------- Fallback: verified round-11 fused kernel (no workspace) ----------------
__global__ __launch_bounds__(256) void fused_pool_patch(const float* __restrict__ x,
                                                        float* __restrict__ out) {
    const int b = xcd_swz(blockIdx.x, NBLK2);
    const int i  = b / 150;
    const int rem = b % 150;
    const int j  = rem / 5;
    const int ks = rem % 5;
    const int wave = threadIdx.x >> 6;
    const int lane = threadIdx.x & 63;
    const int dg = wave & 1;
    const int wh = wave >> 1;
    const int c4 = lane & 3;
    const int wl = lane >> 2;
    const int w = 24 * ks + 14 * wh + wl;
    const int dbase = 4 * i + 4 * dg;
    const int hbase = 4 * j;
    float4 acc[2][4];
#pragma unroll
    for (int p = 0; p < 2; ++p)
#pragma unroll
        for (int hh = 0; hh < 4; ++hh)
            acc[p][hh] = make_float4(-INFINITY, -INFINITY, -INFINITY, -INFINITY);
#pragma unroll
    for (int dl = 0; dl < 6; ++dl) {
        const size_t rowb = ((size_t)(dbase + dl) * D0 + hbase) * D0 + w;
        float4 rw[10];
#pragma unroll
        for (int hl = 0; hl < 10; ++hl)
            rw[hl] = *reinterpret_cast<const float4*>(&x[(rowb + hl * D0) * NC + c4 * 4]);
#pragma unroll
        for (int hl = 0; hl < 10; ++hl) {
#pragma unroll
            for (int hpl = 0; hpl < 4; ++hpl) {
                if (hl >= 2 * hpl && hl <= 2 * hpl + 3) {
                    if (dl <= 3) acc[0][hpl] = f4max(acc[0][hpl], rw[hl]);
                    if (dl >= 2) acc[1][hpl] = f4max(acc[1][hpl], rw[hl]);
                }
            }
        }
    }
    __shared__ float plds[4 * 4 * 14 * 16];
    const bool emit = ((wl & 1) == 0) && (wl <= 12);
    const int wpl0 = 7 * wh + (wl >> 1);
#pragma unroll
    for (int dpl = 0; dpl < 2; ++dpl) {
#pragma unroll
        for (int hpl = 0; hpl < 4; ++hpl) {
            const float4 v = acc[dpl][hpl];
            const float4 m1 = f4max(v, shfl_down4(v, 4));
            const float4 m2 = f4max(m1, shfl_down4(m1, 8));
            if (emit) {
                const int a = 2 * dg + dpl;
                *reinterpret_cast<float4*>(&plds[(((a * 4 + hpl) * 14 + wpl0) * 4 + c4) * 4]) = m2;
            }
        }
    }
    __syncthreads();
    const size_t obase = ((size_t)(i * 30 + j) * 30 + 6 * ks) * 256;
#pragma unroll
    for (int rr = 0; rr < 6; ++rr) {
        const int f = threadIdx.x + 256 * rr;
        const int rowq = (f >> 2) & 63;
        const int c4e = f & 3;
        const int a  = rowq >> 4;
        const int bbq = (rowq >> 2) & 3;
        const int cc = rowq & 3;
        const int wpl = 2 * (f >> 8) + cc;
        const f32x4 v = *reinterpret_cast<const f32x4*>(
            &plds[(((a * 4 + bbq) * 14 + wpl) * 4 + c4e) * 4]);
        __builtin_nontemporal_store(v, reinterpret_cast<f32x4*>(&out[(obase + f) * 4]));
    }
}

extern "C" void kernel_launch(void* const* d_in, const int* in_sizes, int n_in,
                              void* d_out, int out_size, void* d_ws, size_t ws_size,
                              hipStream_t stream) {
    const float* x = (const float*)d_in[0];
    float* out = (float*)d_out;

    const size_t hwp2_bytes = (size_t)DPE * DPE * DPE * NC * sizeof(float);  // 16 MB
    if (ws_size >= hwp2_bytes) {
        float* hwp2 = (float*)d_ws;
        hw_pool_pair<<<NBLK1, 576, 0, stream>>>(x, hwp2);
        slab_gather2<<<NBLK2, 256, 0, stream>>>(hwp2, out);
    } else {
        fused_pool_patch<<<NBLK2, 256, 0, stream>>>(x, out);
    }
}

// Round 16
// 50.732 us; speedup vs baseline: 1.1347x; 1.0233x over previous
//
#include <hip/hip_runtime.h>
#include <math.h>

// x: [128,128,128,16] f32 ; MaxPool3d win 4 stride 2 -> pooled [63,63,63,16]
// patches: 30^3 cubes of 4^3 at stride 2 -> out (27000, 64, 16) f32
// Identity: pooled[dp] = max(pair[dp], pair[dp+1]), pair[t] = max(d-rows 2t,2t+1).
// Phase 1: streaming hw-pool + d-PAIR fold -> hwp2[t=63][hp=63][wp=63][c=16] (16 MB)
// Phase 2: per-patch-run slab gather: LDS slab [5][4][14], 2-way d-fold, NT emit.
// (Round-13 configuration — best measured: 50.6 us. r14 NT-loads: 57.6; r15 HSPL=8: 51.9.)
#define D0 128
#define NC 16
#define DPE 63
#define NP 30
#define NBLK2 (NP*NP*5)    // 4500

typedef float f32x4 __attribute__((ext_vector_type(4)));

__device__ __forceinline__ float4 f4max(float4 a, float4 b) {
    return make_float4(fmaxf(a.x, b.x), fmaxf(a.y, b.y), fmaxf(a.z, b.z), fmaxf(a.w, b.w));
}
__device__ __forceinline__ float4 shfl_down4(float4 v, int d) {
    return make_float4(__shfl_down(v.x, d, 64), __shfl_down(v.y, d, 64),
                       __shfl_down(v.z, d, 64), __shfl_down(v.w, d, 64));
}

// ---------------- Phase 1: dense-streaming hw-pool + d-pair fold ----------------
// grid = (t, hq) = 63*4 = 252 blocks, 576 threads = 9 waves; wave s owns w=14s..14s+15.
// Block streams h-rows of d-slices 2t and 2t+1 (two ~300KB contiguous runs).
__global__ __launch_bounds__(576) void hw_pool_pair(const float* __restrict__ x,
                                                    float* __restrict__ hwp2) {
    const int t = blockIdx.x / 4;        // d-pair index 0..62
    const int hq = blockIdx.x & 3;       // h-quarter
    const int s = threadIdx.x >> 6;      // wave 0..8
    const int lane = threadIdx.x & 63;
    const int wl = lane >> 2;            // 0..15
    const int c4 = lane & 3;
    const int w = 14 * s + wl;           // 0..127

    const int tt0 = 16 * hq;                       // h-pair range [tt0, tt1]
    const int tt1 = min(16 * hq + 16, DPE);        // emit hp = tt-1 in [16hq, ...]

    const size_t rowstep = (size_t)D0 * NC;        // 2048 floats per h row
    const float* base0 = x + ((size_t)(2 * t) * D0 * D0 + w) * NC + c4 * 4;
    const float* base1 = base0 + (size_t)D0 * D0 * NC;

    const bool emit = ((wl & 1) == 0) && (wl <= 12);
    const int wp = 7 * s + (wl >> 1);              // 0..62, each exactly once
    float* outb = hwp2 + ((size_t)t * DPE * DPE + wp) * NC + c4 * 4;

#define LDR(B, h) (*reinterpret_cast<const float4*>((B) + (size_t)min(h, D0 - 1) * rowstep))
    // depth-2 pipeline over h-pairs; each h-pair = 4 rows (2 h x 2 d)
    float4 c0 = LDR(base0, 2 * tt0),     c1 = LDR(base0, 2 * tt0 + 1);
    float4 c2 = LDR(base1, 2 * tt0),     c3 = LDR(base1, 2 * tt0 + 1);
    float4 n0 = LDR(base0, 2 * tt0 + 2), n1 = LDR(base0, 2 * tt0 + 3);
    float4 n2 = LDR(base1, 2 * tt0 + 2), n3 = LDR(base1, 2 * tt0 + 3);
    float4 prev = make_float4(-INFINITY, -INFINITY, -INFINITY, -INFINITY);

    for (int tt = tt0; tt <= tt1; ++tt) {
        float4 m0 = LDR(base0, 2 * tt + 4), m1 = LDR(base0, 2 * tt + 5);
        float4 m2 = LDR(base1, 2 * tt + 4), m3 = LDR(base1, 2 * tt + 5);
        const float4 pair = f4max(f4max(c0, c1), f4max(c2, c3));  // d-pair+h-pair fold
        if (tt > tt0) {
            const float4 win = f4max(prev, pair);              // h rows 2(tt-1)..2tt+1
            const float4 s1 = f4max(win, shfl_down4(win, 4));  // + w+1
            const float4 s2 = f4max(s1, shfl_down4(s1, 8));    // + w+2, w+3
            if (emit)
                *reinterpret_cast<float4*>(outb + (size_t)(tt - 1) * (DPE * NC)) = s2;
        }
        prev = pair;
        c0 = n0; c1 = n1; c2 = n2; c3 = n3;
        n0 = m0; n1 = m1; n2 = m2; n3 = m3;
    }
#undef LDR
}

// ---------------- Phase 2: slab gather with 2-way d-fold ----------------
// block = (i, j, ks): slab = hwp2[2i..2i+4][2j..2j+3][12ks..12ks+13][:] -> LDS
// (wp padded 14->15), pooled[2i+a] = max(slab[a], slab[a+1]); 6 patches NT-emitted.
__global__ __launch_bounds__(256) void slab_gather2(const float* __restrict__ hwp2,
                                                    float* __restrict__ out) {
    // bijective XCD swizzle (nwg=4500, nwg%8=4)
    const int q = NBLK2 >> 3, r = NBLK2 & 7;
    const int xcd = blockIdx.x & 7, idx = blockIdx.x >> 3;
    const int b = (xcd < r ? xcd * (q + 1) : r * (q + 1) + (xcd - r) * q) + idx;

    const int i = b / 150;
    const int rem = b % 150;
    const int j = rem / 5;
    const int ks = rem % 5;
    const int tid = threadIdx.x;

    __shared__ float4 slab[5 * 4 * 15 * 4];   // [t_l][hp_l][wp_l pad15][c4] = 19200 B

    // stage 1120 float4s; global runs of 56 f4 = 896B per (t_l, hp_l)
    for (int it = 0; it < 5; ++it) {
        const int f = tid + 256 * it;
        if (f < 1120) {
            const int t_l = f / 224;           // [5]
            const int r224 = f - t_l * 224;
            const int hp_l = r224 / 56;        // [4]
            const int r56 = r224 - hp_l * 56;
            const int wp_l = r56 >> 2;         // [14]
            const int c4 = f & 3;
            const size_t g = ((size_t)(2 * i + t_l) * DPE + (2 * j + hp_l)) * DPE
                           + (12 * ks + wp_l);
            slab[((t_l * 4 + hp_l) * 15 + wp_l) * 4 + c4] =
                *reinterpret_cast<const float4*>(&hwp2[g * NC + c4 * 4]);
        }
    }
    __syncthreads();

    // emit: tid -> (a, bb, cc, c4); kl = patch within run of 6
    const int a  = (tid >> 6) & 3;
    const int bb = (tid >> 4) & 3;
    const int cc = (tid >> 2) & 3;
    const int c4 = tid & 3;
    const size_t obase = ((size_t)(i * NP + j) * NP + 6 * ks) * 256;  // float4 units
#pragma unroll
    for (int kl = 0; kl < 6; ++kl) {
        const int wp_l = 2 * kl + cc;
        const int base16 = ((a * 4 + bb) * 15 + wp_l) * 4 + c4;
        const float4 m = f4max(slab[base16], slab[base16 + 240]);  // 240 = 4*15*4
        const f32x4 v = {m.x, m.y, m.z, m.w};
        __builtin_nontemporal_store(v, reinterpret_cast<f32x4*>(&out[(obase + kl * 256 + tid) * 4]));
    }
}

// ---------------- Fallback: verified round-11 fused kernel (no workspace) ----------------
__global__ __launch_bounds__(256) void fused_pool_patch(const float* __restrict__ x,
                                                        float* __restrict__ out) {
    const int q = NBLK2 >> 3, r = NBLK2 & 7;
    const int xcd = blockIdx.x & 7, idx = blockIdx.x >> 3;
    const int b = (xcd < r ? xcd * (q + 1) : r * (q + 1) + (xcd - r) * q) + idx;
    const int i  = b / 150;
    const int rem = b % 150;
    const int j  = rem / 5;
    const int ks = rem % 5;
    const int wave = threadIdx.x >> 6;
    const int lane = threadIdx.x & 63;
    const int dg = wave & 1;
    const int wh = wave >> 1;
    const int c4 = lane & 3;
    const int wl = lane >> 2;
    const int w = 24 * ks + 14 * wh + wl;
    const int dbase = 4 * i + 4 * dg;
    const int hbase = 4 * j;
    float4 acc[2][4];
#pragma unroll
    for (int p = 0; p < 2; ++p)
#pragma unroll
        for (int hh = 0; hh < 4; ++hh)
            acc[p][hh] = make_float4(-INFINITY, -INFINITY, -INFINITY, -INFINITY);
#pragma unroll
    for (int dl = 0; dl < 6; ++dl) {
        const size_t rowb = ((size_t)(dbase + dl) * D0 + hbase) * D0 + w;
        float4 rw[10];
#pragma unroll
        for (int hl = 0; hl < 10; ++hl)
            rw[hl] = *reinterpret_cast<const float4*>(&x[(rowb + hl * D0) * NC + c4 * 4]);
#pragma unroll
        for (int hl = 0; hl < 10; ++hl) {
#pragma unroll
            for (int hpl = 0; hpl < 4; ++hpl) {
                if (hl >= 2 * hpl && hl <= 2 * hpl + 3) {
                    if (dl <= 3) acc[0][hpl] = f4max(acc[0][hpl], rw[hl]);
                    if (dl >= 2) acc[1][hpl] = f4max(acc[1][hpl], rw[hl]);
                }
            }
        }
    }
    __shared__ float plds[4 * 4 * 14 * 16];
    const bool emit = ((wl & 1) == 0) && (wl <= 12);
    const int wpl0 = 7 * wh + (wl >> 1);
#pragma unroll
    for (int dpl = 0; dpl < 2; ++dpl) {
#pragma unroll
        for (int hpl = 0; hpl < 4; ++hpl) {
            const float4 v = acc[dpl][hpl];
            const float4 m1 = f4max(v, shfl_down4(v, 4));
            const float4 m2 = f4max(m1, shfl_down4(m1, 8));
            if (emit) {
                const int a = 2 * dg + dpl;
                *reinterpret_cast<float4*>(&plds[(((a * 4 + hpl) * 14 + wpl0) * 4 + c4) * 4]) = m2;
            }
        }
    }
    __syncthreads();
    const size_t obase = ((size_t)(i * 30 + j) * 30 + 6 * ks) * 256;
#pragma unroll
    for (int rr = 0; rr < 6; ++rr) {
        const int f = threadIdx.x + 256 * rr;
        const int rowq = (f >> 2) & 63;
        const int c4e = f & 3;
        const int a  = rowq >> 4;
        const int bbq = (rowq >> 2) & 3;
        const int cc = rowq & 3;
        const int wpl = 2 * (f >> 8) + cc;
        const f32x4 v = *reinterpret_cast<const f32x4*>(
            &plds[(((a * 4 + bbq) * 14 + wpl) * 4 + c4e) * 4]);
        __builtin_nontemporal_store(v, reinterpret_cast<f32x4*>(&out[(obase + f) * 4]));
    }
}

extern "C" void kernel_launch(void* const* d_in, const int* in_sizes, int n_in,
                              void* d_out, int out_size, void* d_ws, size_t ws_size,
                              hipStream_t stream) {
    const float* x = (const float*)d_in[0];
    float* out = (float*)d_out;

    const size_t hwp2_bytes = (size_t)DPE * DPE * DPE * NC * sizeof(float);  // 16 MB
    if (ws_size >= hwp2_bytes) {
        float* hwp2 = (float*)d_ws;
        hw_pool_pair<<<DPE * 4, 576, 0, stream>>>(x, hwp2);
        slab_gather2<<<NBLK2, 256, 0, stream>>>(hwp2, out);
    } else {
        fused_pool_patch<<<NBLK2, 256, 0, stream>>>(x, out);
    }
}